// Round 6
// baseline (296.377 us; speedup 1.0000x reference)
//
#include <hip/hip_runtime.h>
#include <hip/hip_bf16.h>

// ---------------------------------------------------------------------------
// AttentionModel B=4,S=2048,E=1024 single-head, fp32 in/out. bf16 MFMA GEMMs.
// R6: __launch_bounds__(256,4) on all GEMMs (was 2) — 4 blocks/CU co-resident
//     so barrier-drain stalls of one block are hidden by others' MFMA waves
//     (m114 overlap; 60 VGPR + 64 AGPR = 124/wave, 4 waves fit unified RF).
//     cvt3+transpose merged into one `prep` dispatch (6 -> 5 kernels; R5
//     accounting shows ~90us of inter-dispatch overhead).
// Pipeline:
//   1) prep: cvt q,k,v fp32->bf16 + transpose W's fp32->bf16 [out][in]
//   2) qkv_proj: q,k row-major bf16; v transposed vT[b][e][s]
//   3) scores GEMM -> P = exp2(q.k * c) bf16
//   4) row_lsum: lsum[r] = sum(P[r,:])
//   5) PV GEMM -> out = (P @ vT^T) / lsum
// ---------------------------------------------------------------------------

typedef __bf16 bf16_t;
typedef bf16_t bf16x8 __attribute__((ext_vector_type(8)));
typedef bf16_t bf16x4 __attribute__((ext_vector_type(4)));
typedef float  f32x4  __attribute__((ext_vector_type(4)));

typedef const __attribute__((address_space(1))) unsigned gl_uint;
typedef __attribute__((address_space(3))) unsigned lds_uint;

#define BM 128
#define BN 128
#define BK 64

__device__ __forceinline__ void gload_lds16(const void* g, void* l) {
  __builtin_amdgcn_global_load_lds((gl_uint*)g, (lds_uint*)l, 16, 0, 0);
}

// Inner MFMA over one staged 128x64 bf16 tile pair (XOR-swizzled 16B blocks,
// 8 slots/row; slot c holds global seg c^(row&7)). Verified 0 conflicts (R2).
__device__ __forceinline__ void mfma_tile(const bf16_t* As, const bf16_t* Bs,
                                          f32x4 acc[4][4]) {
  const int lane = threadIdx.x & 63;
  const int quad = lane >> 4;
  const int l15  = lane & 15;
  const int wid  = threadIdx.x >> 6;
  const int wm   = (wid >> 1) * 64;
  const int wn   = (wid & 1) * 64;
  const int csw  = l15 & 7;
#pragma unroll
  for (int ks = 0; ks < 2; ++ks) {
    const int sg = ks * 4 + quad;
    const int c  = (sg ^ csw) * 8;
    bf16x8 fa[4], fb[4];
#pragma unroll
    for (int i = 0; i < 4; ++i)
      fa[i] = *(const bf16x8*)&As[(wm + i * 16 + l15) * BK + c];
#pragma unroll
    for (int i = 0; i < 4; ++i)
      fb[i] = *(const bf16x8*)&Bs[(wn + i * 16 + l15) * BK + c];
#pragma unroll
    for (int mi = 0; mi < 4; ++mi)
#pragma unroll
      for (int ni = 0; ni < 4; ++ni)
        acc[mi][ni] = __builtin_amdgcn_mfma_f32_16x16x32_bf16(
            fa[mi], fb[ni], acc[mi][ni], 0, 0, 0);
  }
}

// bf16 A/B core: both tiles staged via global_load_lds width=16.
__device__ __forceinline__ void gemm_core_bf16(
    const bf16_t* __restrict__ Ab, const bf16_t* __restrict__ Bb,
    const int K, bf16_t* As, bf16_t* Bs, f32x4 acc[4][4])
{
  const int tid = threadIdx.x;
  for (int kt = 0; kt < K; kt += BK) {
#pragma unroll
    for (int j = 0; j < 4; ++j) {
      const int lin = j * 256 + tid;
      const int row = lin >> 3;
      const int seg = (lin & 7) ^ (row & 7);
      gload_lds16(Ab + (size_t)row * K + kt + seg * 8, &As[lin * 8]);
    }
#pragma unroll
    for (int j = 0; j < 4; ++j) {
      const int lin = j * 256 + tid;
      const int row = lin >> 3;
      const int seg = (lin & 7) ^ (row & 7);
      gload_lds16(Bb + (size_t)row * K + kt + seg * 8, &Bs[lin * 8]);
    }
    __syncthreads();
    mfma_tile(As, Bs, acc);
    __syncthreads();
  }
}

// Fused Q/K/V projection (bf16 A and W). 1536 blocks, 1-D grid.
// XCD swizzle: xcd=L&7 owns 3 supertiles; each supertile = 64 blocks covering
// all 8 weight-col x 8 A-row tiles of one z — A/W reuse stays in one L2.
__global__ __launch_bounds__(256, 4)
void qkv_proj(const bf16_t* __restrict__ qb, const bf16_t* __restrict__ kb,
              const bf16_t* __restrict__ vb, const bf16_t* __restrict__ Wqt,
              const bf16_t* __restrict__ Wkt, const bf16_t* __restrict__ Wvt,
              const float* __restrict__ bq, const float* __restrict__ bk,
              const float* __restrict__ bv, bf16_t* __restrict__ qp,
              bf16_t* __restrict__ kp, bf16_t* __restrict__ vT)
{
  __shared__ __align__(16) bf16_t As[BM * BK];
  __shared__ __align__(16) bf16_t Bs[BN * BK];

  const int L = blockIdx.x;
  const int g = L >> 3;
  const int gst = (L & 7) * 3 + (g >> 6);   // [0,24)
  const int z  = gst >> 3;
  const int sy = gst & 7;
  const int w  = g & 63;
  const int bx = w & 7;
  const int by = sy * 8 + (w >> 3);

  const bf16_t* A    = (z == 0) ? qb : (z == 1) ? kb : vb;
  const bf16_t* W    = (z == 0) ? Wqt : (z == 1) ? Wkt : Wvt;
  const float*  bias = (z == 0) ? bq : (z == 1) ? bk : bv;
  const int K = 1024, N = 1024;
  const bf16_t* Ab = A + (size_t)by * BM * K;
  const bf16_t* Bb = W + (size_t)bx * BN * K;

  f32x4 acc[4][4];
  const f32x4 z4 = {0.f, 0.f, 0.f, 0.f};
#pragma unroll
  for (int i = 0; i < 4; ++i)
#pragma unroll
    for (int j = 0; j < 4; ++j) acc[i][j] = z4;

  gemm_core_bf16(Ab, Bb, K, As, Bs, acc);

  const int lane = threadIdx.x & 63;
  const int quad = lane >> 4;
  const int l15  = lane & 15;
  const int wid  = threadIdx.x >> 6;
  const int wm = (wid >> 1) * 64, wn = (wid & 1) * 64;
  const int m0 = by * BM, n0 = bx * BN;
#pragma unroll
  for (int mi = 0; mi < 4; ++mi) {
#pragma unroll
    for (int ni = 0; ni < 4; ++ni) {
      const int gn = n0 + wn + ni * 16 + l15;
      const int gm = m0 + wm + mi * 16 + quad * 4;
      const float bv_ = bias[gn];
      f32x4 a = acc[mi][ni];
      if (z < 2) {
        bf16_t* C = (z == 0) ? qp : kp;
#pragma unroll
        for (int r = 0; r < 4; ++r)
          C[(size_t)(gm + r) * N + gn] = (bf16_t)(a[r] + bv_);
      } else {
        const int b = gm >> 11;   // S=2048
        const int s = gm & 2047;
        bf16x4 o;
#pragma unroll
        for (int r = 0; r < 4; ++r) o[r] = (bf16_t)(a[r] + bv_);
        *(bf16x4*)&vT[((size_t)b * N + gn) * 2048 + s] = o;
      }
    }
  }
}

// MODE 0: scores (1024 blocks) — P = exp2(acc*cexp) bf16 (no sums here).
// MODE 1: PV (512 blocks) — C fp32 = acc / lsum[row].
template <int MODE>
__global__ __launch_bounds__(256, 4)
void gemm_att(const bf16_t* __restrict__ A, const bf16_t* __restrict__ Bt,
              void* __restrict__ Cv, const float* __restrict__ lsum,
              const int M, const int N, const int K,
              const long long sA, const long long sB, const long long sC)
{
  __shared__ __align__(16) bf16_t As[BM * BK];
  __shared__ __align__(16) bf16_t Bs[BN * BK];

  const int L = blockIdx.x;
  int bx, by, bz;
  if (MODE == 0) {
    const int g = L >> 3;
    const int gst = (L & 7) * 2 + (g >> 6);  // [0,16)
    bz = gst >> 2;
    const int s2 = gst & 3;
    const int w = g & 63;
    bx = (s2 & 1) * 8 + (w & 7);
    by = (s2 >> 1) * 8 + (w >> 3);
  } else {
    const int xcd = L & 7;
    const int w = (L >> 3) & 63;
    bz = xcd >> 1;
    bx = w & 7;
    by = (xcd & 1) * 8 + (w >> 3);
  }

  const bf16_t* Ab = A + (size_t)bz * sA + (size_t)by * BM * K;
  const bf16_t* Bb = Bt + (size_t)bz * sB + (size_t)bx * BN * K;

  f32x4 acc[4][4];
  const f32x4 z4 = {0.f, 0.f, 0.f, 0.f};
#pragma unroll
  for (int i = 0; i < 4; ++i)
#pragma unroll
    for (int j = 0; j < 4; ++j) acc[i][j] = z4;

  gemm_core_bf16(Ab, Bb, K, As, Bs, acc);

  const int lane = threadIdx.x & 63;
  const int quad = lane >> 4;
  const int l15  = lane & 15;
  const int wid  = threadIdx.x >> 6;
  const int wm = (wid >> 1) * 64, wn = (wid & 1) * 64;
  const int m0 = by * BM, n0 = bx * BN;

  if (MODE == 0) {
    const float cexp = 0.03125f * 1.4426950408889634f;  // (1/32)*log2(e)
    bf16_t* C = (bf16_t*)Cv + (size_t)bz * sC;
#pragma unroll
    for (int mi = 0; mi < 4; ++mi) {
      const int gm = m0 + wm + mi * 16 + quad * 4;
#pragma unroll
      for (int ni = 0; ni < 4; ++ni) {
        const int gn = n0 + wn + ni * 16 + l15;
        f32x4 a = acc[mi][ni];
#pragma unroll
        for (int r = 0; r < 4; ++r)
          C[(size_t)(gm + r) * N + gn] = (bf16_t)exp2f(a[r] * cexp);
      }
    }
  } else {
    float* C = (float*)Cv + (size_t)bz * sC;
    const float* lrow = lsum + (size_t)bz * M;
#pragma unroll
    for (int mi = 0; mi < 4; ++mi) {
      const int gm = m0 + wm + mi * 16 + quad * 4;
      float il[4];
#pragma unroll
      for (int r = 0; r < 4; ++r) il[r] = 1.0f / lrow[gm + r];
#pragma unroll
      for (int ni = 0; ni < 4; ++ni) {
        const int gn = n0 + wn + ni * 16 + l15;
        f32x4 a = acc[mi][ni];
#pragma unroll
        for (int r = 0; r < 4; ++r)
          C[(size_t)(gm + r) * N + gn] = a[r] * il[r];
      }
    }
  }
}

// lsum[r] = sum over P[r,:] (2048 bf16). One wave per row, 4 rows/block.
__global__ __launch_bounds__(256)
void row_lsum(const bf16_t* __restrict__ P, float* __restrict__ lsum) {
  const int tid = threadIdx.x, lane = tid & 63, wid = tid >> 6;
  const size_t row = (size_t)blockIdx.x * 4 + wid;
  const bf16_t* src = P + row * 2048;
  float s = 0.f;
#pragma unroll
  for (int j = 0; j < 4; ++j) {
    const bf16x8 v = *(const bf16x8*)&src[(j * 64 + lane) * 8];
#pragma unroll
    for (int t = 0; t < 8; ++t) s += (float)v[t];
  }
#pragma unroll
  for (int o = 32; o; o >>= 1) s += __shfl_xor(s, o);
  if (lane == 0) lsum[row] = s;
}

// Merged prep: blocks [0,24576): fp32->bf16 cvt of q/k/v (1024 elem/block);
// blocks [24576,25344): 64x64 transpose-cvt tiles of Wq/Wk/Wv.
__global__ __launch_bounds__(256)
void prep(const float* __restrict__ q, const float* __restrict__ k,
          const float* __restrict__ v, const float* __restrict__ Wq,
          const float* __restrict__ Wk, const float* __restrict__ Wv,
          bf16_t* __restrict__ qo, bf16_t* __restrict__ ko,
          bf16_t* __restrict__ vo, bf16_t* __restrict__ Wqt,
          bf16_t* __restrict__ Wkt, bf16_t* __restrict__ Wvt) {
  const int L = blockIdx.x;
  const int tid = threadIdx.x;
  if (L < 24576) {
    const int z = L >> 13;            // 8192 blocks per tensor
    const int blk = L & 8191;
    const float* in = (z == 0) ? q : (z == 1) ? k : v;
    bf16_t* out = (z == 0) ? qo : (z == 1) ? ko : vo;
    const size_t i = ((size_t)blk * 256 + tid) * 4;
    const float4 w = *(const float4*)(in + i);
    bf16x4 o;
    o[0] = (bf16_t)w.x; o[1] = (bf16_t)w.y; o[2] = (bf16_t)w.z; o[3] = (bf16_t)w.w;
    *(bf16x4*)(out + i) = o;
  } else {
    const int t = L - 24576;          // [0,768)
    const int z = t >> 8;
    const int wi = t & 255;
    const float* W = (z == 0) ? Wq : (z == 1) ? Wk : Wv;
    bf16_t* Wt = (z == 0) ? Wqt : (z == 1) ? Wkt : Wvt;
    __shared__ float tile[64][65];
    const int n0 = (wi & 15) * 64;
    const int k0 = (wi >> 4) * 64;
#pragma unroll
    for (int it = 0; it < 16; ++it) {
      const int idx = it * 256 + tid;
      const int r = idx >> 6, c = idx & 63;
      tile[r][c] = W[(size_t)(k0 + r) * 1024 + n0 + c];
    }
    __syncthreads();
#pragma unroll
    for (int it = 0; it < 16; ++it) {
      const int idx = it * 256 + tid;
      const int r = idx >> 6, c = idx & 63;
      Wt[(size_t)(n0 + r) * 1024 + k0 + c] = (bf16_t)tile[c][r];
    }
  }
}

extern "C" void kernel_launch(void* const* d_in, const int* in_sizes, int n_in,
                              void* d_out, int out_size, void* d_ws, size_t ws_size,
                              hipStream_t stream) {
  const int B = 4, S = 2048, E = 1024;
  const size_t BSE = (size_t)B * S * E;
  const size_t EE  = (size_t)E * E;

  const float* q_in = (const float*)d_in[0];
  const float* k_in = (const float*)d_in[1];
  const float* v_in = (const float*)d_in[2];
  const float* Wq = (const float*)d_in[3];
  const float* bq = (const float*)d_in[4];
  const float* Wk = (const float*)d_in[5];
  const float* bk = (const float*)d_in[6];
  const float* Wv = (const float*)d_in[7];
  const float* bv = (const float*)d_in[8];
  float* out = (float*)d_out;

  char* ws = (char*)d_ws;
  bf16_t* Wqt = (bf16_t*)ws;                      // 2MB each
  bf16_t* Wkt = Wqt + EE;
  bf16_t* Wvt = Wkt + EE;
  bf16_t* qb  = Wvt + EE;                         // 16.8MB each
  bf16_t* kb  = qb + BSE;
  bf16_t* vb  = kb + BSE;
  bf16_t* qp  = vb + BSE;
  bf16_t* kp  = qp + BSE;
  bf16_t* vT  = kp + BSE;                         // [B][E][S]
  bf16_t* P   = vT + BSE;                         // [B][S][S] 33.5MB
  float*  lsum = (float*)(P + (size_t)B * S * S); // 32KB; total ~140MB

  prep<<<25344, 256, 0, stream>>>(q_in, k_in, v_in, Wq, Wk, Wv,
                                  qb, kb, vb, Wqt, Wkt, Wvt);

  qkv_proj<<<1536, 256, 0, stream>>>(qb, kb, vb, Wqt, Wkt, Wvt,
                                     bq, bk, bv, qp, kp, vT);

  gemm_att<0><<<1024, 256, 0, stream>>>(
      qp, kp, P, nullptr, S, S, E,
      (long long)S * E, (long long)S * E, (long long)S * S);

  row_lsum<<<(B * S) / 4, 256, 0, stream>>>(P, lsum);

  gemm_att<1><<<512, 256, 0, stream>>>(
      P, vT, out, lsum, S, E, S,
      (long long)S * S, (long long)E * S, (long long)S * E);

  (void)in_sizes; (void)n_in; (void)out_size; (void)ws_size;
}

// Round 7
// 285.300 us; speedup vs baseline: 1.0388x; 1.0388x over previous
//
#include <hip/hip_runtime.h>
#include <hip/hip_bf16.h>

// ---------------------------------------------------------------------------
// AttentionModel B=4,S=2048,E=1024 single-head, fp32 in/out. bf16 MFMA GEMMs.
// R7: revert launch_bounds to (256,2) everywhere (R6's (256,4) cost qkv
//     59->73us with no occupancy gain — plateau is not occupancy-starved).
//     Fold row-sum into PV via ones-MFMA: acc_l = mfma(fa, 1.0) gives row
//     sums in exactly the C-layout row mapping -> il=1/acc_l in epilogue.
//     Kills row_lsum kernel + its 33.5MB P re-read + one gap. 4 dispatches.
// Pipeline:
//   1) prep: cvt q,k,v fp32->bf16 + transpose W's fp32->bf16 [out][in]
//   2) qkv_proj: q,k row-major bf16; v transposed vT[b][e][s]
//   3) scores GEMM -> P = exp2(q.k * c) bf16
//   4) PV GEMM -> out = (P @ vT^T) / rowsum(P)   (rowsum via ones-MFMA)
// ---------------------------------------------------------------------------

typedef __bf16 bf16_t;
typedef bf16_t bf16x8 __attribute__((ext_vector_type(8)));
typedef bf16_t bf16x4 __attribute__((ext_vector_type(4)));
typedef float  f32x4  __attribute__((ext_vector_type(4)));

typedef const __attribute__((address_space(1))) unsigned gl_uint;
typedef __attribute__((address_space(3))) unsigned lds_uint;

#define BM 128
#define BN 128
#define BK 64

__device__ __forceinline__ void gload_lds16(const void* g, void* l) {
  __builtin_amdgcn_global_load_lds((gl_uint*)g, (lds_uint*)l, 16, 0, 0);
}

// Inner MFMA over one staged 128x64 bf16 tile pair (XOR-swizzled 16B blocks,
// 8 slots/row; slot c holds global seg c^(row&7)). Verified 0 conflicts (R2).
// LSUM: additionally acc_l[mi] += fa[mi] . ones  (row-sums of A-tile).
template <bool LSUM>
__device__ __forceinline__ void mfma_tile(const bf16_t* As, const bf16_t* Bs,
                                          f32x4 acc[4][4], f32x4 acc_l[4]) {
  const int lane = threadIdx.x & 63;
  const int quad = lane >> 4;
  const int l15  = lane & 15;
  const int wid  = threadIdx.x >> 6;
  const int wm   = (wid >> 1) * 64;
  const int wn   = (wid & 1) * 64;
  const int csw  = l15 & 7;
  bf16x8 ones;
  if (LSUM) {
#pragma unroll
    for (int t = 0; t < 8; ++t) ones[t] = (bf16_t)1.0f;
  }
#pragma unroll
  for (int ks = 0; ks < 2; ++ks) {
    const int sg = ks * 4 + quad;
    const int c  = (sg ^ csw) * 8;
    bf16x8 fa[4], fb[4];
#pragma unroll
    for (int i = 0; i < 4; ++i)
      fa[i] = *(const bf16x8*)&As[(wm + i * 16 + l15) * BK + c];
#pragma unroll
    for (int i = 0; i < 4; ++i)
      fb[i] = *(const bf16x8*)&Bs[(wn + i * 16 + l15) * BK + c];
#pragma unroll
    for (int mi = 0; mi < 4; ++mi)
#pragma unroll
      for (int ni = 0; ni < 4; ++ni)
        acc[mi][ni] = __builtin_amdgcn_mfma_f32_16x16x32_bf16(
            fa[mi], fb[ni], acc[mi][ni], 0, 0, 0);
    if (LSUM) {
#pragma unroll
      for (int mi = 0; mi < 4; ++mi)
        acc_l[mi] = __builtin_amdgcn_mfma_f32_16x16x32_bf16(
            fa[mi], ones, acc_l[mi], 0, 0, 0);
    }
  }
}

// bf16 A/B core: both tiles staged via global_load_lds width=16.
template <bool LSUM>
__device__ __forceinline__ void gemm_core_bf16(
    const bf16_t* __restrict__ Ab, const bf16_t* __restrict__ Bb,
    const int K, bf16_t* As, bf16_t* Bs, f32x4 acc[4][4], f32x4 acc_l[4])
{
  const int tid = threadIdx.x;
  for (int kt = 0; kt < K; kt += BK) {
#pragma unroll
    for (int j = 0; j < 4; ++j) {
      const int lin = j * 256 + tid;
      const int row = lin >> 3;
      const int seg = (lin & 7) ^ (row & 7);
      gload_lds16(Ab + (size_t)row * K + kt + seg * 8, &As[lin * 8]);
    }
#pragma unroll
    for (int j = 0; j < 4; ++j) {
      const int lin = j * 256 + tid;
      const int row = lin >> 3;
      const int seg = (lin & 7) ^ (row & 7);
      gload_lds16(Bb + (size_t)row * K + kt + seg * 8, &Bs[lin * 8]);
    }
    __syncthreads();
    mfma_tile<LSUM>(As, Bs, acc, acc_l);
    __syncthreads();
  }
}

// Fused Q/K/V projection (bf16 A and W). 1536 blocks, 1-D grid.
// XCD swizzle: xcd=L&7 owns 3 supertiles; each supertile = 64 blocks covering
// all 8 weight-col x 8 A-row tiles of one z — A/W reuse stays in one L2.
__global__ __launch_bounds__(256, 2)
void qkv_proj(const bf16_t* __restrict__ qb, const bf16_t* __restrict__ kb,
              const bf16_t* __restrict__ vb, const bf16_t* __restrict__ Wqt,
              const bf16_t* __restrict__ Wkt, const bf16_t* __restrict__ Wvt,
              const float* __restrict__ bq, const float* __restrict__ bk,
              const float* __restrict__ bv, bf16_t* __restrict__ qp,
              bf16_t* __restrict__ kp, bf16_t* __restrict__ vT)
{
  __shared__ __align__(16) bf16_t As[BM * BK];
  __shared__ __align__(16) bf16_t Bs[BN * BK];

  const int L = blockIdx.x;
  const int g = L >> 3;
  const int gst = (L & 7) * 3 + (g >> 6);   // [0,24)
  const int z  = gst >> 3;
  const int sy = gst & 7;
  const int w  = g & 63;
  const int bx = w & 7;
  const int by = sy * 8 + (w >> 3);

  const bf16_t* A    = (z == 0) ? qb : (z == 1) ? kb : vb;
  const bf16_t* W    = (z == 0) ? Wqt : (z == 1) ? Wkt : Wvt;
  const float*  bias = (z == 0) ? bq : (z == 1) ? bk : bv;
  const int K = 1024, N = 1024;
  const bf16_t* Ab = A + (size_t)by * BM * K;
  const bf16_t* Bb = W + (size_t)bx * BN * K;

  f32x4 acc[4][4];
  const f32x4 z4 = {0.f, 0.f, 0.f, 0.f};
#pragma unroll
  for (int i = 0; i < 4; ++i)
#pragma unroll
    for (int j = 0; j < 4; ++j) acc[i][j] = z4;

  gemm_core_bf16<false>(Ab, Bb, K, As, Bs, acc, nullptr);

  const int lane = threadIdx.x & 63;
  const int quad = lane >> 4;
  const int l15  = lane & 15;
  const int wid  = threadIdx.x >> 6;
  const int wm = (wid >> 1) * 64, wn = (wid & 1) * 64;
  const int m0 = by * BM, n0 = bx * BN;
#pragma unroll
  for (int mi = 0; mi < 4; ++mi) {
#pragma unroll
    for (int ni = 0; ni < 4; ++ni) {
      const int gn = n0 + wn + ni * 16 + l15;
      const int gm = m0 + wm + mi * 16 + quad * 4;
      const float bv_ = bias[gn];
      f32x4 a = acc[mi][ni];
      if (z < 2) {
        bf16_t* C = (z == 0) ? qp : kp;
#pragma unroll
        for (int r = 0; r < 4; ++r)
          C[(size_t)(gm + r) * N + gn] = (bf16_t)(a[r] + bv_);
      } else {
        const int b = gm >> 11;   // S=2048
        const int s = gm & 2047;
        bf16x4 o;
#pragma unroll
        for (int r = 0; r < 4; ++r) o[r] = (bf16_t)(a[r] + bv_);
        *(bf16x4*)&vT[((size_t)b * N + gn) * 2048 + s] = o;
      }
    }
  }
}

// MODE 0: scores (1024 blocks) — P = exp2(acc*cexp) bf16.
// MODE 1: PV (512 blocks) — C fp32 = acc / rowsum, rowsum via ones-MFMA.
template <int MODE>
__global__ __launch_bounds__(256, 2)
void gemm_att(const bf16_t* __restrict__ A, const bf16_t* __restrict__ Bt,
              void* __restrict__ Cv,
              const int M, const int N, const int K,
              const long long sA, const long long sB, const long long sC)
{
  __shared__ __align__(16) bf16_t As[BM * BK];
  __shared__ __align__(16) bf16_t Bs[BN * BK];

  const int L = blockIdx.x;
  int bx, by, bz;
  if (MODE == 0) {
    const int g = L >> 3;
    const int gst = (L & 7) * 2 + (g >> 6);  // [0,16)
    bz = gst >> 2;
    const int s2 = gst & 3;
    const int w = g & 63;
    bx = (s2 & 1) * 8 + (w & 7);
    by = (s2 >> 1) * 8 + (w >> 3);
  } else {
    const int xcd = L & 7;
    const int w = (L >> 3) & 63;
    bz = xcd >> 1;
    bx = w & 7;
    by = (xcd & 1) * 8 + (w >> 3);
  }

  const bf16_t* Ab = A + (size_t)bz * sA + (size_t)by * BM * K;
  const bf16_t* Bb = Bt + (size_t)bz * sB + (size_t)bx * BN * K;

  f32x4 acc[4][4];
  f32x4 acc_l[4];
  const f32x4 z4 = {0.f, 0.f, 0.f, 0.f};
#pragma unroll
  for (int i = 0; i < 4; ++i) {
    acc_l[i] = z4;
#pragma unroll
    for (int j = 0; j < 4; ++j) acc[i][j] = z4;
  }

  gemm_core_bf16<MODE == 1>(Ab, Bb, K, As, Bs, acc, acc_l);

  const int lane = threadIdx.x & 63;
  const int quad = lane >> 4;
  const int l15  = lane & 15;
  const int wid  = threadIdx.x >> 6;
  const int wm = (wid >> 1) * 64, wn = (wid & 1) * 64;
  const int m0 = by * BM, n0 = bx * BN;

  if (MODE == 0) {
    const float cexp = 0.03125f * 1.4426950408889634f;  // (1/32)*log2(e)
    bf16_t* C = (bf16_t*)Cv + (size_t)bz * sC;
#pragma unroll
    for (int mi = 0; mi < 4; ++mi) {
      const int gm = m0 + wm + mi * 16 + quad * 4;
#pragma unroll
      for (int ni = 0; ni < 4; ++ni) {
        const int gn = n0 + wn + ni * 16 + l15;
        f32x4 a = acc[mi][ni];
#pragma unroll
        for (int r = 0; r < 4; ++r)
          C[(size_t)(gm + r) * N + gn] = (bf16_t)exp2f(a[r] * cexp);
      }
    }
  } else {
    float* C = (float*)Cv + (size_t)bz * sC;
#pragma unroll
    for (int mi = 0; mi < 4; ++mi) {
      const int gm = m0 + wm + mi * 16 + quad * 4;
      // acc_l[mi][r] = sum_k P[row,k]: C-layout rows == epilogue rows.
      float il[4];
#pragma unroll
      for (int r = 0; r < 4; ++r) il[r] = 1.0f / acc_l[mi][r];
#pragma unroll
      for (int ni = 0; ni < 4; ++ni) {
        const int gn = n0 + wn + ni * 16 + l15;
        f32x4 a = acc[mi][ni];
#pragma unroll
        for (int r = 0; r < 4; ++r)
          C[(size_t)(gm + r) * N + gn] = a[r] * il[r];
      }
    }
  }
}

// Merged prep: blocks [0,24576): fp32->bf16 cvt of q/k/v (1024 elem/block);
// blocks [24576,25344): 64x64 transpose-cvt tiles of Wq/Wk/Wv.
__global__ __launch_bounds__(256)
void prep(const float* __restrict__ q, const float* __restrict__ k,
          const float* __restrict__ v, const float* __restrict__ Wq,
          const float* __restrict__ Wk, const float* __restrict__ Wv,
          bf16_t* __restrict__ qo, bf16_t* __restrict__ ko,
          bf16_t* __restrict__ vo, bf16_t* __restrict__ Wqt,
          bf16_t* __restrict__ Wkt, bf16_t* __restrict__ Wvt) {
  const int L = blockIdx.x;
  const int tid = threadIdx.x;
  if (L < 24576) {
    const int z = L >> 13;            // 8192 blocks per tensor
    const int blk = L & 8191;
    const float* in = (z == 0) ? q : (z == 1) ? k : v;
    bf16_t* out = (z == 0) ? qo : (z == 1) ? ko : vo;
    const size_t i = ((size_t)blk * 256 + tid) * 4;
    const float4 w = *(const float4*)(in + i);
    bf16x4 o;
    o[0] = (bf16_t)w.x; o[1] = (bf16_t)w.y; o[2] = (bf16_t)w.z; o[3] = (bf16_t)w.w;
    *(bf16x4*)(out + i) = o;
  } else {
    const int t = L - 24576;          // [0,768)
    const int z = t >> 8;
    const int wi = t & 255;
    const float* W = (z == 0) ? Wq : (z == 1) ? Wk : Wv;
    bf16_t* Wt = (z == 0) ? Wqt : (z == 1) ? Wkt : Wvt;
    __shared__ float tile[64][65];
    const int n0 = (wi & 15) * 64;
    const int k0 = (wi >> 4) * 64;
#pragma unroll
    for (int it = 0; it < 16; ++it) {
      const int idx = it * 256 + tid;
      const int r = idx >> 6, c = idx & 63;
      tile[r][c] = W[(size_t)(k0 + r) * 1024 + n0 + c];
    }
    __syncthreads();
#pragma unroll
    for (int it = 0; it < 16; ++it) {
      const int idx = it * 256 + tid;
      const int r = idx >> 6, c = idx & 63;
      Wt[(size_t)(n0 + r) * 1024 + k0 + c] = (bf16_t)tile[c][r];
    }
  }
}

extern "C" void kernel_launch(void* const* d_in, const int* in_sizes, int n_in,
                              void* d_out, int out_size, void* d_ws, size_t ws_size,
                              hipStream_t stream) {
  const int B = 4, S = 2048, E = 1024;
  const size_t BSE = (size_t)B * S * E;
  const size_t EE  = (size_t)E * E;

  const float* q_in = (const float*)d_in[0];
  const float* k_in = (const float*)d_in[1];
  const float* v_in = (const float*)d_in[2];
  const float* Wq = (const float*)d_in[3];
  const float* bq = (const float*)d_in[4];
  const float* Wk = (const float*)d_in[5];
  const float* bk = (const float*)d_in[6];
  const float* Wv = (const float*)d_in[7];
  const float* bv = (const float*)d_in[8];
  float* out = (float*)d_out;

  char* ws = (char*)d_ws;
  bf16_t* Wqt = (bf16_t*)ws;                      // 2MB each
  bf16_t* Wkt = Wqt + EE;
  bf16_t* Wvt = Wkt + EE;
  bf16_t* qb  = Wvt + EE;                         // 16.8MB each
  bf16_t* kb  = qb + BSE;
  bf16_t* vb  = kb + BSE;
  bf16_t* qp  = vb + BSE;
  bf16_t* kp  = qp + BSE;
  bf16_t* vT  = kp + BSE;                         // [B][E][S]
  bf16_t* P   = vT + BSE;                         // [B][S][S] 33.5MB; ~140MB

  prep<<<25344, 256, 0, stream>>>(q_in, k_in, v_in, Wq, Wk, Wv,
                                  qb, kb, vb, Wqt, Wkt, Wvt);

  qkv_proj<<<1536, 256, 0, stream>>>(qb, kb, vb, Wqt, Wkt, Wvt,
                                     bq, bk, bv, qp, kp, vT);

  gemm_att<0><<<1024, 256, 0, stream>>>(
      qp, kp, P, S, S, E,
      (long long)S * E, (long long)S * E, (long long)S * S);

  gemm_att<1><<<512, 256, 0, stream>>>(
      P, vT, out, S, E, S,
      (long long)S * S, (long long)E * S, (long long)S * E);

  (void)in_sizes; (void)n_in; (void)out_size; (void)ws_size;
}